// Round 10
// baseline (89.906 us; speedup 1.0000x reference)
//
#include <hip/hip_runtime.h>

// Problem constants (KANLayer): B=1024, I=128, O=128, H=5
#define Bsz 1024
#define Isz 128
#define Osz 128
#define Hsz 5
#define GB 32    // batches per block
#define NG (Bsz / GB)
#define UF 4     // batches in flight

// ---------------------------------------------------------------------------
// DPP wave64 sum -> lane 63. All VALU (v_add_f32_dpp), zero DS-pipe.
// ---------------------------------------------------------------------------
template <int CTRL>
__device__ __forceinline__ float dpp_add(float s) {
    int t = __builtin_amdgcn_update_dpp(0, __builtin_bit_cast(int, s),
                                        CTRL, 0xf, 0xf, true);
    return s + __builtin_bit_cast(float, t);
}
__device__ __forceinline__ float wave_sum64_lane63(float s) {
    s = dpp_add<0xB1>(s);    // quad_perm xor1
    s = dpp_add<0x4E>(s);    // quad_perm xor2
    s = dpp_add<0x141>(s);   // row_half_mirror (xor 4)
    s = dpp_add<0x140>(s);   // row_mirror      (xor 8)
    s = dpp_add<0x142>(s);   // row_bcast:15
    s = dpp_add<0x143>(s);   // row_bcast:31
    return s;                // lane 63 = full sum
}
__device__ __forceinline__ float lane63(float s) {
    return __builtin_bit_cast(float,
        __builtin_amdgcn_readlane(__builtin_bit_cast(int, s), 63));
}

// ---------------------------------------------------------------------------
// Edge-stationary kernel, NO x-staging (R10).
// For fixed batch b, lane l reads x[b][i0+l] -- 64 consecutive floats, i.e.
// perfectly coalesced per-wave global loads. x is L2-resident (512 KB; total
// re-read 32 MB ~= 1 us of L2 BW), so the former LDS tile (4 global loads +
// 4 ds_writes + 2 barriers + 32 ds_read_b32/thread) was pure overhead.
// Full unroll of the 32-batch loop lets the scheduler hoist the 32 loads
// arbitrarily early (they also cover the param-gather latency).
// Thread <-> one edge (o,i); 46 params in VGPRs (gathered once).
// Block = 4 waves = 2 o's x 128 i; grid 2048 blocks; out written once.
// ---------------------------------------------------------------------------
__global__ __launch_bounds__(256, 4)
void kan_kernel(const float* __restrict__ x,
                const float* __restrict__ W1, const float* __restrict__ B1,
                const float* __restrict__ W2, const float* __restrict__ B2,
                const float* __restrict__ W3, const float* __restrict__ B3,
                float* __restrict__ out) {
    __shared__ float partial[4 * GB];     // 512 B: per-wave reduced rows

    const int tid = threadIdx.x;
    const int ob  = blockIdx.x & 63;      // o-pair index (fastest)
    const int g   = blockIdx.x >> 6;      // batch group 0..31
    const int b0  = g * GB;
    const int w   = tid >> 6;             // wave 0..3
    const int l   = tid & 63;             // lane
    const int o   = 2 * ob + (w >> 1);    // waves 0,1 -> o0; waves 2,3 -> o1
    const int i   = 64 * (w & 1) + l;     // i-half per wave
    const int e   = o * Isz + i;

    // --- my edge's 46 params -> VGPRs, gathered once ---
    float w1[Hsz], b1[Hsz], w2[Hsz * Hsz], b2[Hsz], w3[Hsz];
    #pragma unroll
    for (int h = 0; h < Hsz; ++h) {
        w1[h] = W1[(size_t)e * Hsz + h];
        b1[h] = B1[(size_t)e * Hsz + h];
        b2[h] = B2[(size_t)e * Hsz + h];
        w3[h] = W3[(size_t)e * Hsz + h];
    }
    #pragma unroll
    for (int j = 0; j < Hsz * Hsz; ++j) w2[j] = W2[(size_t)e * Hsz * Hsz + j];

    // batch-invariant b3 term: wave-reduced once
    const float s3 = lane63(wave_sum64_lane63(B3[e]));

    // column pointer: this thread's i within batch rows b0..b0+GB-1
    const float* __restrict__ xcol = x + (size_t)b0 * Isz + i;

    float res = 0.0f;   // out-partial for batch b0+l (l < GB), this i-half

    #pragma unroll
    for (int bl = 0; bl < GB; bl += UF) {
        float y[UF];
        #pragma unroll
        for (int u = 0; u < UF; ++u) {
            const float a = xcol[(size_t)(bl + u) * Isz];   // coalesced, L2-hit

            // layer 1: scalar -> H, leaky_relu(0.01)
            float h1[Hsz];
            #pragma unroll
            for (int h = 0; h < Hsz; ++h) {
                float v = fmaf(a, w1[h], b1[h]);
                h1[h] = fmaxf(v, 0.01f * v);
            }
            // layer 2 (H->H, lrelu) + layer 3 (H->1, b3 hoisted out)
            float yy = 0.0f;
            #pragma unroll
            for (int k = 0; k < Hsz; ++k) {
                float s = b2[k];
                #pragma unroll
                for (int h = 0; h < Hsz; ++h)
                    s = fmaf(h1[h], w2[k * Hsz + h], s);
                s = fmaxf(s, 0.01f * s);
                yy = fmaf(s, w3[k], yy);
            }
            y[u] = yy;
        }

        // DPP reduce each chain; park lane-63 total in lane bl+u.
        #pragma unroll
        for (int u = 0; u < UF; ++u) {
            const float s = wave_sum64_lane63(y[u]);
            const float tot = lane63(s);
            if (l == bl + u) res = tot;
        }
    }

    if (l < GB) partial[w * GB + l] = res + s3;
    __syncthreads();

    // combine i-half waves and store: 64 outputs per block, each written once
    if (tid < 2 * GB) {
        const int bl = tid & (GB - 1);
        const int oo = tid >> 5;
        const float v = partial[(2 * oo) * GB + bl] + partial[(2 * oo + 1) * GB + bl];
        out[(size_t)(b0 + bl) * Osz + (2 * ob + oo)] = v;
    }
}

extern "C" void kernel_launch(void* const* d_in, const int* in_sizes, int n_in,
                              void* d_out, int out_size, void* d_ws, size_t ws_size,
                              hipStream_t stream) {
    const float* x  = (const float*)d_in[0];
    const float* W1 = (const float*)d_in[1];
    const float* B1 = (const float*)d_in[2];
    const float* W2 = (const float*)d_in[3];
    const float* B2 = (const float*)d_in[4];
    const float* W3 = (const float*)d_in[5];
    const float* B3 = (const float*)d_in[6];
    float* out = (float*)d_out;

    const dim3 grid((Osz / 2) * NG);   // 64 o-pairs x 32 batch groups = 2048 blocks
    kan_kernel<<<grid, dim3(256), 0, stream>>>(x, W1, B1, W2, B2, W3, B3, out);
}